// Round 5
// baseline (164269.714 us; speedup 1.0000x reference)
//
#include <hip/hip_runtime.h>

#define T_   256
#define B_   64
#define H_   1024
#define Hh_  512
#define L_   2
#define K1_  1536
#define MAXF 0.875f
#define NBLK 128
#define NT   1024

// ---- ws float offsets ----
#define OFF_WZR1 0u          // [2][64 blk][1536][16]
#define OFF_WG1  3145728u    // [2][64 blk][1536][8]
#define OFF_WZR2 4718592u
#define OFF_WG2  7864320u
#define OFF_XT   9437184u    // [2 buf][1024 k][64 r]
#define OFF_HT   9568256u    // [2 l][2 buf][1024 n][64 r]
#define OFF_ZT   9830400u    // [2 l][512 n][64 r]
#define OFF_RHT  9895936u    // [2 l][512 n][64 r]
#define OFF_CTR  9961472u    // barrier counter (u32)

// Retile: src [L][K1][N] -> dst [L][N/C blocks][K1][C]
__global__ __launch_bounds__(256) void retile_w(const float* __restrict__ src,
                                                float* __restrict__ dst,
                                                int N, int C) {
    size_t tid = (size_t)blockIdx.x * 256 + threadIdx.x;
    size_t total = (size_t)L_ * K1_ * N;
    if (tid >= total) return;
    int c = (int)(tid % C);
    int k = (int)((tid / C) % K1_);
    int b = (int)((tid / ((size_t)C * K1_)) % (N / C));
    int l = (int)(tid / ((size_t)C * K1_ * (N / C)));
    dst[tid] = src[((size_t)l * K1_ + k) * N + b * C + c];
}

// Device-coherent (cross-XCD) activation access — no cache fences ever needed.
__device__ __forceinline__ float ld_coh(const float* p) {
    return __hip_atomic_load(p, __ATOMIC_RELAXED, __HIP_MEMORY_SCOPE_AGENT);
}
__device__ __forceinline__ void st_coh(float* p, float v) {
    __hip_atomic_store(p, v, __ATOMIC_RELAXED, __HIP_MEMORY_SCOPE_AGENT);
}

// Fence-free grid barrier: monotonic counter, no reset, no L2 invalidate.
__device__ __forceinline__ void gbar(unsigned* ctr, unsigned* target) {
    *target += NBLK;
    __syncthreads();
    if (threadIdx.x == 0) {
        __hip_atomic_fetch_add(ctr, 1u, __ATOMIC_RELAXED, __HIP_MEMORY_SCOPE_AGENT);
        while (__hip_atomic_load(ctr, __ATOMIC_RELAXED, __HIP_MEMORY_SCOPE_AGENT) < *target)
            __builtin_amdgcn_s_sleep(1);
    }
    __syncthreads();
}

// C[64 r][C cols] = A[64][1536] @ Wt[1536][C].
// W streams through LDS in 6 chunks of 256 k, double-buffered (coalesced
// float4 staging -> BW-bound, latency amortized per chunk not per k).
// A register-double-buffered coherent loads, one chunk ahead.
// k-split 16 ways over waves per chunk; LDS-atomic cross-wave reduce.
template<int C>
__device__ __forceinline__ float phase_gemm(const float* __restrict__ Axlo,
                                            const float* __restrict__ Ahi,
                                            const float* __restrict__ Wt,
                                            float* __restrict__ ldsW,
                                            float* __restrict__ red) {
    const int tid  = threadIdx.x;
    const int lane = tid & 63;
    const int w    = tid >> 6;                 // wave 0..15
    constexpr int KCH = 256, NCH = K1_ / KCH;  // 6 chunks
    constexpr int CHF = KCH * C;               // floats per chunk
    constexpr int CHV = CHF / 4;               // float4 per chunk (<= 1024)
    const int kw0 = w * 16;                    // wave's k-offset inside chunk

    for (int i = tid; i < 64 * (C + 1); i += NT) red[i] = 0.f;

    float acc[C];
#pragma unroll
    for (int c = 0; c < C; ++c) acc[c] = 0.f;

    float4* buf4 = (float4*)ldsW;
    const float4* W4 = (const float4*)Wt;
    float4 pref;
    if (tid < CHV) pref = W4[tid];             // W chunk 0

    float avc[16], avn[16];
#pragma unroll
    for (int kk = 0; kk < 16; ++kk)            // A chunk 0 (k < 1024 -> Axlo)
        avc[kk] = ld_coh(Axlo + (size_t)(kw0 + kk) * 64 + lane);

    for (int j = 0; j < NCH; ++j) {
        if (tid < CHV) buf4[(j & 1) * CHV + tid] = pref;
        if (j + 1 < NCH) {
            const int kb = (j + 1) * KCH;
            const float* Ap = (kb < H_) ? (Axlo + (size_t)kb * 64)
                                        : (Ahi + (size_t)(kb - H_) * 64);
#pragma unroll
            for (int kk = 0; kk < 16; ++kk)
                avn[kk] = ld_coh(Ap + (size_t)(kw0 + kk) * 64 + lane);
            if (tid < CHV) pref = W4[(size_t)(j + 1) * CHV + tid];
        }
        __syncthreads();                       // chunk j staged
        const float* lw = ldsW + (j & 1) * CHF + kw0 * C;
#pragma unroll
        for (int kk = 0; kk < 16; ++kk) {
#pragma unroll
            for (int c4 = 0; c4 < C / 4; ++c4) {
                const float4 wv = *(const float4*)&lw[kk * C + c4 * 4]; // broadcast
                acc[c4 * 4 + 0] = fmaf(avc[kk], wv.x, acc[c4 * 4 + 0]);
                acc[c4 * 4 + 1] = fmaf(avc[kk], wv.y, acc[c4 * 4 + 1]);
                acc[c4 * 4 + 2] = fmaf(avc[kk], wv.z, acc[c4 * 4 + 2]);
                acc[c4 * 4 + 3] = fmaf(avc[kk], wv.w, acc[c4 * 4 + 3]);
            }
        }
        __syncthreads();                       // consumers done before next write
#pragma unroll
        for (int kk = 0; kk < 16; ++kk) avc[kk] = avn[kk];
    }
#pragma unroll
    for (int c = 0; c < C; ++c) atomicAdd(&red[lane * (C + 1) + c], acc[c]);
    __syncthreads();
    float v = 0.f;
    if (tid < 64 * C) v = red[(tid / C) * (C + 1) + (tid % C)];
    return v;
}

__global__ __launch_bounds__(NT) void revgru_main(
    const int* __restrict__ seq, const float* __restrict__ h0,
    const float* __restrict__ emb,
    const float* __restrict__ bzr1, const float* __restrict__ bg1,
    const float* __restrict__ bzr2, const float* __restrict__ bg2,
    float* __restrict__ ws, float* __restrict__ out)
{
    const int bi = blockIdx.x, tid = threadIdx.x;
    const int l = (bi >= 64) ? 1 : 0, bl = bi & 63;
    __shared__ float ldsW[2 * 256 * 16];   // 32 KB double-buffered W chunks
    __shared__ float red[64 * 17];         // 4.4 KB padded reduce
    unsigned target = 0;

    float* xT  = ws + OFF_XT;
    float* hT  = ws + OFF_HT;
    float* zT  = ws + OFF_ZT;
    float* rhT = ws + OFF_RHT;
    unsigned* ctr = (unsigned*)(ws + OFF_CTR);

    const float* Wz1  = ws + OFF_WZR1 + ((size_t)l * 64 + bl) * K1_ * 16;
    const float* Wg1l = ws + OFF_WG1  + ((size_t)l * 64 + bl) * K1_ * 8;
    const float* Wz2  = ws + OFF_WZR2 + ((size_t)l * 64 + bl) * K1_ * 16;
    const float* Wg2l = ws + OFF_WG2  + ((size_t)l * 64 + bl) * K1_ * 8;

    const int gtid = bi * NT + tid;            // 0..131071
    {   // init: hT[l][buf=1] = h0^T (step t=0 reads buf 1)
        int ll = gtid >> 16, rem = gtid & 65535, r = rem >> 10, n = rem & 1023;
        st_coh(&hT[(((size_t)ll * 2 + 1) * H_ + n) * 64 + r], h0[gtid]);
        if (bi < 64) {  // xT[0] = emb gather for t=0
            int k = gtid >> 6, rr = gtid & 63;
            st_coh(&xT[gtid], emb[(size_t)seq[rr] * H_ + k]);
        }
    }
    gbar(ctr, &target);

    // Pipelined: L0 blocks process t=s, L1 blocks t=s-1.
    for (int s = 0; s <= T_; ++s) {
        const int t = (l == 0) ? s : s - 1;
        const bool act = (t >= 0) && (t < T_);
        const int buf = t & 1;
        float* hC = hT + ((size_t)l * 2 + buf) * (H_ * 64);        // new state
        float* hP = hT + ((size_t)l * 2 + (buf ^ 1)) * (H_ * 64);  // old state
        const float* Ax = (l == 0) ? (xT + (size_t)buf * (H_ * 64))
                                   : (hT + (size_t)buf * (H_ * 64));  // L0 h(t)
        float* zl  = zT  + (size_t)l * Hh_ * 64;
        float* rhl = rhT + (size_t)l * Hh_ * 64;

        // ---- P1: zr1 = [x, h2_old] @ Wzr1 ----
        if (act) {
            float v = phase_gemm<16>(Ax, hP + Hh_ * 64, Wz1, ldsW, red);
            int r = tid >> 4, c = tid & 15, n = bl * 16 + c;
            v += bzr1[l * H_ + n];
            float sg = 1.f / (1.f + __expf(-v));
            if (n < Hh_) st_coh(&zl[n * 64 + r], sg * MAXF + (1.f - MAXF));
            else st_coh(&rhl[(n - Hh_) * 64 + r],
                        sg * ld_coh(&hP[(size_t)n * 64 + r]));     // r1*h2_old
            if (l == 0 && t + 1 < T_) {   // prefetch x(t+1)
                int k = gtid >> 6, rr = gtid & 63;
                st_coh(&xT[(size_t)((t + 1) & 1) * (H_ * 64) + k * 64 + rr],
                       emb[(size_t)seq[(t + 1) * B_ + rr] * H_ + k]);
            }
        }
        gbar(ctr, &target);
        // ---- P2: g1; h1_new = z1*h1_old + (1-z1)*g1 ----
        if (act) {
            float v = phase_gemm<8>(Ax, rhl, Wg1l, ldsW, red);
            if (tid < 512) {
                int r = tid >> 3, c = tid & 7, n = bl * 8 + c;
                float g = tanhf(v + bg1[l * Hh_ + n]);
                float z = ld_coh(&zl[n * 64 + r]);
                float h1o = ld_coh(&hP[(size_t)n * 64 + r]);
                st_coh(&hC[(size_t)n * 64 + r], z * h1o + (1.f - z) * g);
            }
        }
        gbar(ctr, &target);
        // ---- P3: zr2 = [x, h1_new] @ Wzr2 ----
        if (act) {
            float v = phase_gemm<16>(Ax, hC, Wz2, ldsW, red);
            int r = tid >> 4, c = tid & 15, n = bl * 16 + c;
            v += bzr2[l * H_ + n];
            float sg = 1.f / (1.f + __expf(-v));
            if (n < Hh_) st_coh(&zl[n * 64 + r], sg * MAXF + (1.f - MAXF));
            else st_coh(&rhl[(n - Hh_) * 64 + r],
                        sg * ld_coh(&hC[(size_t)(n - Hh_) * 64 + r])); // r2*h1n
        }
        gbar(ctr, &target);
        // ---- P4: g2; h2_new = z2*h2_old + (1-z2)*g2 ----
        if (act) {
            float v = phase_gemm<8>(Ax, rhl, Wg2l, ldsW, red);
            if (tid < 512) {
                int r = tid >> 3, c = tid & 7, n = bl * 8 + c;
                float g = tanhf(v + bg2[l * Hh_ + n]);
                float z = ld_coh(&zl[n * 64 + r]);
                float h2o = ld_coh(&hP[(size_t)(Hh_ + n) * 64 + r]);
                st_coh(&hC[(size_t)(Hh_ + n) * 64 + r], z * h2o + (1.f - z) * g);
            }
        }
        gbar(ctr, &target);
    }
    {   // out[l][r][n] = hT[l][1][n][r]  (t=255 -> buf 1 for both layers)
        int ll = gtid >> 16, rem = gtid & 65535, r = rem >> 10, n = rem & 1023;
        out[gtid] = ld_coh(&hT[(((size_t)ll * 2 + 1) * H_ + n) * 64 + r]);
    }
}

extern "C" void kernel_launch(void* const* d_in, const int* in_sizes, int n_in,
                              void* d_out, int out_size, void* d_ws, size_t ws_size,
                              hipStream_t stream) {
    (void)in_sizes; (void)n_in; (void)out_size; (void)ws_size;
    const int*   seq  = (const int*)  d_in[0];
    const float* h0   = (const float*)d_in[1];
    const float* emb  = (const float*)d_in[2];
    const float* Wzr1 = (const float*)d_in[3];
    const float* bzr1 = (const float*)d_in[4];
    const float* Wg1  = (const float*)d_in[5];
    const float* bg1  = (const float*)d_in[6];
    const float* Wzr2 = (const float*)d_in[7];
    const float* bzr2 = (const float*)d_in[8];
    const float* Wg2  = (const float*)d_in[9];
    const float* bg2  = (const float*)d_in[10];
    float* out = (float*)d_out;
    float* ws  = (float*)d_ws;

    hipMemsetAsync((char*)d_ws + (size_t)OFF_CTR * 4, 0, 64, stream);
    retile_w<<<12288, 256, 0, stream>>>(Wzr1, ws + OFF_WZR1, H_, 16);
    retile_w<<<6144,  256, 0, stream>>>(Wg1,  ws + OFF_WG1,  Hh_, 8);
    retile_w<<<12288, 256, 0, stream>>>(Wzr2, ws + OFF_WZR2, H_, 16);
    retile_w<<<6144,  256, 0, stream>>>(Wg2,  ws + OFF_WG2,  Hh_, 8);

    void* args[] = { &seq, &h0, &emb, &bzr1, &bg1, &bzr2, &bg2, &ws, &out };
    hipLaunchCooperativeKernel((void*)revgru_main, dim3(NBLK), dim3(NT),
                               args, 0, stream);
}

// Round 6
// 154433.386 us; speedup vs baseline: 1.0637x; 1.0637x over previous
//
#include <hip/hip_runtime.h>

#define T_   256
#define B_   64
#define H_   1024
#define Hh_  512
#define L_   2
#define K1_  1536
#define MAXF 0.875f
#define NBLK 128
#define NT   1024

// ---- ws float offsets ----
#define OFF_WZR1 0u          // [2][64 blk][1536][16]
#define OFF_WG1  3145728u    // [2][64 blk][1536][8]
#define OFF_WZR2 4718592u
#define OFF_WG2  7864320u
#define OFF_XT   9437184u    // [2 buf][1024 k][64 r]
#define OFF_HT   9568256u    // [2 l][2 buf][1024 n][64 r]
#define OFF_ZT   9830400u    // [2 l][512 n][64 r]
#define OFF_RHT  9895936u    // [2 l][512 n][64 r]
#define OFF_CTR  9961472u    // barrier counter (u32)

// Retile: src [L][K1][N] -> dst [L][N/C blocks][K1][C]
__global__ __launch_bounds__(256) void retile_w(const float* __restrict__ src,
                                                float* __restrict__ dst,
                                                int N, int C) {
    size_t tid = (size_t)blockIdx.x * 256 + threadIdx.x;
    size_t total = (size_t)L_ * K1_ * N;
    if (tid >= total) return;
    int c = (int)(tid % C);
    int k = (int)((tid / C) % K1_);
    int b = (int)((tid / ((size_t)C * K1_)) % (N / C));
    int l = (int)(tid / ((size_t)C * K1_ * (N / C)));
    dst[tid] = src[((size_t)l * K1_ + k) * N + b * C + c];
}

// Device-coherent (cross-XCD) activation access — no cache fences ever needed.
__device__ __forceinline__ float ld_coh(const float* p) {
    return __hip_atomic_load(p, __ATOMIC_RELAXED, __HIP_MEMORY_SCOPE_AGENT);
}
__device__ __forceinline__ void st_coh(float* p, float v) {
    __hip_atomic_store(p, v, __ATOMIC_RELAXED, __HIP_MEMORY_SCOPE_AGENT);
}

// Fence-free grid barrier: monotonic counter, no reset, no L2 invalidate.
__device__ __forceinline__ void gbar(unsigned* ctr, unsigned* target) {
    *target += NBLK;
    __syncthreads();
    if (threadIdx.x == 0) {
        __hip_atomic_fetch_add(ctr, 1u, __ATOMIC_RELAXED, __HIP_MEMORY_SCOPE_AGENT);
        while (__hip_atomic_load(ctr, __ATOMIC_RELAXED, __HIP_MEMORY_SCOPE_AGENT) < *target)
            __builtin_amdgcn_s_sleep(1);
    }
    __syncthreads();
}

// C[64 r][C cols] = A[64][1536] @ Wt[1536][C].
// W streams through LDS in 6 chunks of 256 k, double-buffered, staged by one
// coalesced float4/thread and prefetched a chunk ahead (latency amortized).
// A: 16-way k-split over waves; 8+8 intra-chunk register pipeline (load the
// second 8 while FMA-ing the first 8; prefetch next chunk's first 8 between
// halves). Live regs ~40 -> no spill at <=128 VGPRs.
template<int C>
__device__ __forceinline__ float phase_gemm(const float* __restrict__ Axlo,
                                            const float* __restrict__ Ahi,
                                            const float* __restrict__ Wt,
                                            float* __restrict__ ldsW,
                                            float* __restrict__ red) {
    const int tid  = threadIdx.x;
    const int lane = tid & 63;
    const int w    = tid >> 6;                 // wave 0..15
    constexpr int KCH = 256, NCH = K1_ / KCH;  // 6 chunks
    constexpr int CHF = KCH * C;               // floats per chunk
    constexpr int CHV = CHF / 4;               // float4 per chunk (<= 1024)
    const int kw0 = w * 16;                    // wave's k-offset inside chunk

    for (int i = tid; i < 64 * (C + 1); i += NT) red[i] = 0.f;

    float acc[C];
#pragma unroll
    for (int c = 0; c < C; ++c) acc[c] = 0.f;

    float4* buf4 = (float4*)ldsW;
    const float4* W4 = (const float4*)Wt;
    float4 pref;
    if (tid < CHV) pref = W4[tid];             // W chunk 0

    float av0[8], av1[8];
#pragma unroll
    for (int kk = 0; kk < 8; ++kk)             // chunk-0 first half (k<1024)
        av0[kk] = ld_coh(Axlo + (size_t)(kw0 + kk) * 64 + lane);

    for (int j = 0; j < NCH; ++j) {
        if (tid < CHV) buf4[(j & 1) * CHV + tid] = pref;
        if (j + 1 < NCH && tid < CHV) pref = W4[(size_t)(j + 1) * CHV + tid];
        const int kb = j * KCH;
        const float* Ap = (kb < H_) ? (Axlo + (size_t)kb * 64)
                                    : (Ahi + (size_t)(kb - H_) * 64);
#pragma unroll
        for (int kk = 0; kk < 8; ++kk)         // this chunk's second half
            av1[kk] = ld_coh(Ap + (size_t)(kw0 + 8 + kk) * 64 + lane);
        __syncthreads();                       // chunk j W staged
        const float* lw = ldsW + (j & 1) * CHF + kw0 * C;
#pragma unroll
        for (int kk = 0; kk < 8; ++kk) {       // FMA first half
#pragma unroll
            for (int c4 = 0; c4 < C / 4; ++c4) {
                const float4 wv = *(const float4*)&lw[kk * C + c4 * 4];
                acc[c4 * 4 + 0] = fmaf(av0[kk], wv.x, acc[c4 * 4 + 0]);
                acc[c4 * 4 + 1] = fmaf(av0[kk], wv.y, acc[c4 * 4 + 1]);
                acc[c4 * 4 + 2] = fmaf(av0[kk], wv.z, acc[c4 * 4 + 2]);
                acc[c4 * 4 + 3] = fmaf(av0[kk], wv.w, acc[c4 * 4 + 3]);
            }
        }
        if (j + 1 < NCH) {                     // prefetch next chunk first half
            const int kbn = (j + 1) * KCH;
            const float* Apn = (kbn < H_) ? (Axlo + (size_t)kbn * 64)
                                          : (Ahi + (size_t)(kbn - H_) * 64);
#pragma unroll
            for (int kk = 0; kk < 8; ++kk)
                av0[kk] = ld_coh(Apn + (size_t)(kw0 + kk) * 64 + lane);
        }
#pragma unroll
        for (int kk = 0; kk < 8; ++kk) {       // FMA second half
#pragma unroll
            for (int c4 = 0; c4 < C / 4; ++c4) {
                const float4 wv = *(const float4*)&lw[(kk + 8) * C + c4 * 4];
                acc[c4 * 4 + 0] = fmaf(av1[kk], wv.x, acc[c4 * 4 + 0]);
                acc[c4 * 4 + 1] = fmaf(av1[kk], wv.y, acc[c4 * 4 + 1]);
                acc[c4 * 4 + 2] = fmaf(av1[kk], wv.z, acc[c4 * 4 + 2]);
                acc[c4 * 4 + 3] = fmaf(av1[kk], wv.w, acc[c4 * 4 + 3]);
            }
        }
        __syncthreads();                       // consumers done before rewrite
    }
#pragma unroll
    for (int c = 0; c < C; ++c) atomicAdd(&red[lane * (C + 1) + c], acc[c]);
    __syncthreads();
    float v = 0.f;
    if (tid < 64 * C) v = red[(tid / C) * (C + 1) + (tid % C)];
    return v;
}

__global__ __launch_bounds__(NT, 4) void revgru_main(
    const int* __restrict__ seq, const float* __restrict__ h0,
    const float* __restrict__ emb,
    const float* __restrict__ bzr1, const float* __restrict__ bg1,
    const float* __restrict__ bzr2, const float* __restrict__ bg2,
    float* __restrict__ ws, float* __restrict__ out)
{
    const int bi = blockIdx.x, tid = threadIdx.x;
    const int l = (bi >= 64) ? 1 : 0, bl = bi & 63;
    __shared__ float ldsW[2 * 256 * 16];   // 32 KB double-buffered W chunks
    __shared__ float red[64 * 17];         // 4.4 KB padded reduce
    unsigned target = 0;

    float* xT  = ws + OFF_XT;
    float* hT  = ws + OFF_HT;
    float* zT  = ws + OFF_ZT;
    float* rhT = ws + OFF_RHT;
    unsigned* ctr = (unsigned*)(ws + OFF_CTR);

    const float* Wz1  = ws + OFF_WZR1 + ((size_t)l * 64 + bl) * K1_ * 16;
    const float* Wg1l = ws + OFF_WG1  + ((size_t)l * 64 + bl) * K1_ * 8;
    const float* Wz2  = ws + OFF_WZR2 + ((size_t)l * 64 + bl) * K1_ * 16;
    const float* Wg2l = ws + OFF_WG2  + ((size_t)l * 64 + bl) * K1_ * 8;

    const int gtid = bi * NT + tid;            // 0..131071
    {   // init: hT[l][buf=1] = h0^T (step t=0 reads buf 1)
        int ll = gtid >> 16, rem = gtid & 65535, r = rem >> 10, n = rem & 1023;
        st_coh(&hT[(((size_t)ll * 2 + 1) * H_ + n) * 64 + r], h0[gtid]);
        if (bi < 64) {  // xT[0] = emb gather for t=0
            int k = gtid >> 6, rr = gtid & 63;
            st_coh(&xT[gtid], emb[(size_t)seq[rr] * H_ + k]);
        }
    }
    gbar(ctr, &target);

    // Pipelined: L0 blocks process t=s, L1 blocks t=s-1.
    for (int s = 0; s <= T_; ++s) {
        const int t = (l == 0) ? s : s - 1;
        const bool act = (t >= 0) && (t < T_);
        const int buf = t & 1;
        float* hC = hT + ((size_t)l * 2 + buf) * (H_ * 64);        // new state
        float* hP = hT + ((size_t)l * 2 + (buf ^ 1)) * (H_ * 64);  // old state
        const float* Ax = (l == 0) ? (xT + (size_t)buf * (H_ * 64))
                                   : (hT + (size_t)buf * (H_ * 64));  // L0 h(t)
        float* zl  = zT  + (size_t)l * Hh_ * 64;
        float* rhl = rhT + (size_t)l * Hh_ * 64;

        // ---- P1: zr1 = [x, h2_old] @ Wzr1 ----
        if (act) {
            float v = phase_gemm<16>(Ax, hP + Hh_ * 64, Wz1, ldsW, red);
            int r = tid >> 4, c = tid & 15, n = bl * 16 + c;
            v += bzr1[l * H_ + n];
            float sg = 1.f / (1.f + __expf(-v));
            if (n < Hh_) st_coh(&zl[n * 64 + r], sg * MAXF + (1.f - MAXF));
            else st_coh(&rhl[(n - Hh_) * 64 + r],
                        sg * ld_coh(&hP[(size_t)n * 64 + r]));     // r1*h2_old
            if (l == 0 && t + 1 < T_) {   // prefetch x(t+1)
                int k = gtid >> 6, rr = gtid & 63;
                st_coh(&xT[(size_t)((t + 1) & 1) * (H_ * 64) + k * 64 + rr],
                       emb[(size_t)seq[(t + 1) * B_ + rr] * H_ + k]);
            }
        }
        gbar(ctr, &target);
        // ---- P2: g1; h1_new = z1*h1_old + (1-z1)*g1 ----
        if (act) {
            float v = phase_gemm<8>(Ax, rhl, Wg1l, ldsW, red);
            if (tid < 512) {
                int r = tid >> 3, c = tid & 7, n = bl * 8 + c;
                float g = tanhf(v + bg1[l * Hh_ + n]);
                float z = ld_coh(&zl[n * 64 + r]);
                float h1o = ld_coh(&hP[(size_t)n * 64 + r]);
                st_coh(&hC[(size_t)n * 64 + r], z * h1o + (1.f - z) * g);
            }
        }
        gbar(ctr, &target);
        // ---- P3: zr2 = [x, h1_new] @ Wzr2 ----
        if (act) {
            float v = phase_gemm<16>(Ax, hC, Wz2, ldsW, red);
            int r = tid >> 4, c = tid & 15, n = bl * 16 + c;
            v += bzr2[l * H_ + n];
            float sg = 1.f / (1.f + __expf(-v));
            if (n < Hh_) st_coh(&zl[n * 64 + r], sg * MAXF + (1.f - MAXF));
            else st_coh(&rhl[(n - Hh_) * 64 + r],
                        sg * ld_coh(&hC[(size_t)(n - Hh_) * 64 + r])); // r2*h1n
        }
        gbar(ctr, &target);
        // ---- P4: g2; h2_new = z2*h2_old + (1-z2)*g2 ----
        if (act) {
            float v = phase_gemm<8>(Ax, rhl, Wg2l, ldsW, red);
            if (tid < 512) {
                int r = tid >> 3, c = tid & 7, n = bl * 8 + c;
                float g = tanhf(v + bg2[l * Hh_ + n]);
                float z = ld_coh(&zl[n * 64 + r]);
                float h2o = ld_coh(&hP[(size_t)(Hh_ + n) * 64 + r]);
                st_coh(&hC[(size_t)(Hh_ + n) * 64 + r], z * h2o + (1.f - z) * g);
            }
        }
        gbar(ctr, &target);
    }
    {   // out[l][r][n] = hT[l][1][n][r]  (t=255 -> buf 1 for both layers)
        int ll = gtid >> 16, rem = gtid & 65535, r = rem >> 10, n = rem & 1023;
        out[gtid] = ld_coh(&hT[(((size_t)ll * 2 + 1) * H_ + n) * 64 + r]);
    }
}

extern "C" void kernel_launch(void* const* d_in, const int* in_sizes, int n_in,
                              void* d_out, int out_size, void* d_ws, size_t ws_size,
                              hipStream_t stream) {
    (void)in_sizes; (void)n_in; (void)out_size; (void)ws_size;
    const int*   seq  = (const int*)  d_in[0];
    const float* h0   = (const float*)d_in[1];
    const float* emb  = (const float*)d_in[2];
    const float* Wzr1 = (const float*)d_in[3];
    const float* bzr1 = (const float*)d_in[4];
    const float* Wg1  = (const float*)d_in[5];
    const float* bg1  = (const float*)d_in[6];
    const float* Wzr2 = (const float*)d_in[7];
    const float* bzr2 = (const float*)d_in[8];
    const float* Wg2  = (const float*)d_in[9];
    const float* bg2  = (const float*)d_in[10];
    float* out = (float*)d_out;
    float* ws  = (float*)d_ws;

    hipMemsetAsync((char*)d_ws + (size_t)OFF_CTR * 4, 0, 64, stream);
    retile_w<<<12288, 256, 0, stream>>>(Wzr1, ws + OFF_WZR1, H_, 16);
    retile_w<<<6144,  256, 0, stream>>>(Wg1,  ws + OFF_WG1,  Hh_, 8);
    retile_w<<<12288, 256, 0, stream>>>(Wzr2, ws + OFF_WZR2, H_, 16);
    retile_w<<<6144,  256, 0, stream>>>(Wg2,  ws + OFF_WG2,  Hh_, 8);

    void* args[] = { &seq, &h0, &emb, &bzr1, &bg1, &bzr2, &bg2, &ws, &out };
    hipLaunchCooperativeKernel((void*)revgru_main, dim3(NBLK), dim3(NT),
                               args, 0, stream);
}